// Round 1
// baseline (1789.100 us; speedup 1.0000x reference)
//
#include <hip/hip_runtime.h>
#include <hip/hip_bf16.h>

typedef __bf16 bf16x8 __attribute__((ext_vector_type(8)));
typedef float  f32x4  __attribute__((ext_vector_type(4)));

// ---------------------------------------------------------------- converts

__global__ __launch_bounds__(256) void f32_to_bf16_kernel(
    const float* __restrict__ in, __bf16* __restrict__ out, size_t n) {
    size_t i = ((size_t)blockIdx.x * 256 + threadIdx.x) * 8;
    if (i >= n) return;
    float4 a = *(const float4*)(in + i);
    float4 b = *(const float4*)(in + i + 4);
    bf16x8 v;
    v[0] = (__bf16)a.x; v[1] = (__bf16)a.y; v[2] = (__bf16)a.z; v[3] = (__bf16)a.w;
    v[4] = (__bf16)b.x; v[5] = (__bf16)b.y; v[6] = (__bf16)b.z; v[7] = (__bf16)b.w;
    *(bf16x8*)(out + i) = v;
}

// W[K][N] fp32  ->  Wt[N][K] bf16   (32x32 LDS tile transpose)
__global__ __launch_bounds__(256) void transpose_to_bf16_kernel(
    const float* __restrict__ W, __bf16* __restrict__ Wt, int K, int N) {
    __shared__ float tile[32][33];
    int n0 = blockIdx.x * 32, k0 = blockIdx.y * 32;
    int tx = threadIdx.x, ty = threadIdx.y;  // 32 x 8
    #pragma unroll
    for (int i = 0; i < 32; i += 8)
        tile[ty + i][tx] = W[(size_t)(k0 + ty + i) * N + n0 + tx];
    __syncthreads();
    #pragma unroll
    for (int i = 0; i < 32; i += 8)
        Wt[(size_t)(n0 + ty + i) * K + k0 + tx] = (__bf16)tile[tx][ty + i];
}

// ---------------------------------------------------------------- GEMM
// C[M][N] = A[M][K](bf16) @ Bt[N][K](bf16)^T + bias[N],  fp32 accumulate.
// 128x128 block tile, BK=32, 4 waves (2x2 of 64x64), mfma_f32_16x16x32_bf16.
#define BM 128
#define BN 128
#define BK 32

template <typename OutT>
__global__ __launch_bounds__(256) void gemm_bt_bias_kernel(
    const __bf16* __restrict__ A, const __bf16* __restrict__ Bt,
    const float* __restrict__ bias, OutT* __restrict__ C,
    int M, int N, int K) {
    __shared__ __bf16 As[BM][BK + 8];  // +8 bf16 pad -> 80B row stride
    __shared__ __bf16 Bs[BN][BK + 8];
    int tid  = threadIdx.x;
    int bm   = blockIdx.x;
    int bn   = blockIdx.y;
    int wave = tid >> 6;
    int lane = tid & 63;
    int wm   = (wave >> 1) * 64;
    int wn   = (wave & 1) * 64;
    int quad = lane >> 4;
    int l16  = lane & 15;
    int arow = tid >> 2;          // 0..63 (two passes: +0, +64)
    int acol = (tid & 3) * 8;     // bf16 elements

    f32x4 acc[4][4];
    f32x4 zero = {0.f, 0.f, 0.f, 0.f};
    #pragma unroll
    for (int i = 0; i < 4; ++i)
        #pragma unroll
        for (int j = 0; j < 4; ++j) acc[i][j] = zero;

    const __bf16* Abase = A  + (size_t)(bm * BM) * K;
    const __bf16* Bbase = Bt + (size_t)(bn * BN) * K;

    for (int k0 = 0; k0 < K; k0 += BK) {
        if (k0) __syncthreads();
        #pragma unroll
        for (int it = 0; it < 2; ++it) {
            int r = arow + it * 64;
            *(uint4*)(&As[r][acol]) = *(const uint4*)(Abase + (size_t)r * K + k0 + acol);
            *(uint4*)(&Bs[r][acol]) = *(const uint4*)(Bbase + (size_t)r * K + k0 + acol);
        }
        __syncthreads();

        bf16x8 a_frag[4], b_frag[4];
        #pragma unroll
        for (int i = 0; i < 4; ++i)
            a_frag[i] = *(bf16x8*)(&As[wm + i * 16 + l16][quad * 8]);
        #pragma unroll
        for (int j = 0; j < 4; ++j)
            b_frag[j] = *(bf16x8*)(&Bs[wn + j * 16 + l16][quad * 8]);
        #pragma unroll
        for (int i = 0; i < 4; ++i)
            #pragma unroll
            for (int j = 0; j < 4; ++j)
                acc[i][j] = __builtin_amdgcn_mfma_f32_16x16x32_bf16(
                    a_frag[i], b_frag[j], acc[i][j], 0, 0, 0);
    }

    // epilogue: D row = quad*4+reg, col = l16 (HW-verified mapping, m89/m91)
    #pragma unroll
    for (int i = 0; i < 4; ++i) {
        int row = bm * BM + wm + i * 16 + quad * 4;
        #pragma unroll
        for (int j = 0; j < 4; ++j) {
            int col  = bn * BN + wn + j * 16 + l16;
            float bv = bias[col];
            #pragma unroll
            for (int r = 0; r < 4; ++r)
                C[(size_t)(row + r) * N + col] = (OutT)(acc[i][j][r] + bv);
        }
    }
}

// ---------------------------------------------------------------- RoPE (in-place, bf16)
__global__ __launch_bounds__(256) void rope_kernel(
    __bf16* __restrict__ buf, const float* __restrict__ cosp,
    const float* __restrict__ sinp, int heads, int rowstride, int S, int total) {
    int idx = blockIdx.x * 256 + threadIdx.x;
    if (idx >= total) return;
    int d  = idx & 63;
    int t2 = idx >> 6;
    int h  = t2 % heads;
    int r  = t2 / heads;      // r = b*S + s
    int s  = r & (S - 1);     // S = 2048 (power of two)
    size_t base = (size_t)r * rowstride + h * 128;
    float x1 = (float)buf[base + d];
    float x2 = (float)buf[base + d + 64];
    float c  = cosp[s * 64 + d];
    float sn = sinp[s * 64 + d];
    buf[base + d]      = (__bf16)(x1 * c - x2 * sn);
    buf[base + d + 64] = (__bf16)(x1 * sn + x2 * c);
}

// ---------------------------------------------------------------- flash attention (fp32 VALU)
// 256 threads = 64 queries x 4 d-groups (32 dims each). K/V tiles of 32 keys in LDS.
#define FA_BQ 64
#define FA_BK 32
#define FA_LDSW 144   // 128 + 4*skew(4): dgrp d-blocks land on disjoint bank groups

__global__ __launch_bounds__(256) void flash_attn_kernel(
    const __bf16* __restrict__ q,   // [B*S][2048], rope applied
    const __bf16* __restrict__ kv,  // [B*S][1024]: k = cols 0..511 (roped), v = 512..1023
    __bf16* __restrict__ vo,        // [B*S][2048]
    const int* __restrict__ causal_p, int B, int S) {
    __shared__ float Ks[FA_BK][FA_LDSW];
    __shared__ float Vs[FA_BK][FA_LDSW];

    int tid     = threadIdx.x;
    int q_local = tid >> 2;
    int dgrp    = tid & 3;
    int d0      = dgrp * 32;
    int qt = blockIdx.x, h = blockIdx.y, b = blockIdx.z;
    int kvh = h >> 2;
    int q0  = qt * FA_BQ;
    int qg  = q0 + q_local;
    int causal = causal_p[0];

    size_t qrow = ((size_t)b * S + qg) * 2048 + h * 128 + d0;
    float qreg[32];
    #pragma unroll
    for (int d = 0; d < 32; d += 8) {
        bf16x8 qv = *(const bf16x8*)(q + qrow + d);
        #pragma unroll
        for (int z = 0; z < 8; ++z) qreg[d + z] = (float)qv[z];
    }

    float o[32];
    #pragma unroll
    for (int d = 0; d < 32; ++d) o[d] = 0.f;
    float m = -1e30f, l = 0.f;
    const float SCALE = 0.08838834764831845f;  // 1/sqrt(128)

    int ntiles = causal ? (q0 / FA_BK + 2) : (S / FA_BK);
    for (int t = 0; t < ntiles; ++t) {
        int j0 = t * FA_BK;
        __syncthreads();
        // stage K,V tile (32 keys x 128 dims), bf16->fp32, skewed layout
        #pragma unroll
        for (int e = tid * 8; e < FA_BK * 128; e += 256 * 8) {
            int j = e >> 7, d = e & 127;
            int off = d + ((d >> 5) << 2);
            size_t row = ((size_t)b * S + j0 + j) * 1024 + kvh * 128 + d;
            bf16x8 kvv = *(const bf16x8*)(kv + row);
            bf16x8 vvv = *(const bf16x8*)(kv + row + 512);
            float4 ka = {(float)kvv[0], (float)kvv[1], (float)kvv[2], (float)kvv[3]};
            float4 kb = {(float)kvv[4], (float)kvv[5], (float)kvv[6], (float)kvv[7]};
            float4 va = {(float)vvv[0], (float)vvv[1], (float)vvv[2], (float)vvv[3]};
            float4 vb = {(float)vvv[4], (float)vvv[5], (float)vvv[6], (float)vvv[7]};
            *(float4*)(&Ks[j][off])     = ka;
            *(float4*)(&Ks[j][off + 4]) = kb;
            *(float4*)(&Vs[j][off])     = va;
            *(float4*)(&Vs[j][off + 4]) = vb;
        }
        __syncthreads();

        // scores
        float s[FA_BK];
        #pragma unroll
        for (int j = 0; j < FA_BK; ++j) {
            const float* kp = &Ks[j][d0 + (dgrp << 2)];
            float a0 = 0.f, a1 = 0.f;
            #pragma unroll
            for (int d = 0; d < 32; d += 8) {
                float4 kv0 = *(const float4*)(kp + d);
                float4 kv1 = *(const float4*)(kp + d + 4);
                a0 += qreg[d + 0] * kv0.x; a0 += qreg[d + 1] * kv0.y;
                a0 += qreg[d + 2] * kv0.z; a0 += qreg[d + 3] * kv0.w;
                a1 += qreg[d + 4] * kv1.x; a1 += qreg[d + 5] * kv1.y;
                a1 += qreg[d + 6] * kv1.z; a1 += qreg[d + 7] * kv1.w;
            }
            float a = a0 + a1;
            a += __shfl_xor(a, 1);
            a += __shfl_xor(a, 2);
            a *= SCALE;
            if (causal && (j0 + j > qg)) a = -1e30f;
            s[j] = a;
        }

        float smax = s[0];
        #pragma unroll
        for (int j = 1; j < FA_BK; ++j) smax = fmaxf(smax, s[j]);
        float m_new = fmaxf(m, smax);
        if (m_new > -1e29f) {
            float alpha = __expf(m - m_new);
            l *= alpha;
            #pragma unroll
            for (int d = 0; d < 32; ++d) o[d] *= alpha;
            #pragma unroll
            for (int j = 0; j < FA_BK; ++j) {
                float pj = __expf(s[j] - m_new);
                l += pj;
                const float* vp = &Vs[j][d0 + (dgrp << 2)];
                #pragma unroll
                for (int d = 0; d < 32; d += 4) {
                    float4 vv = *(const float4*)(vp + d);
                    o[d + 0] += pj * vv.x; o[d + 1] += pj * vv.y;
                    o[d + 2] += pj * vv.z; o[d + 3] += pj * vv.w;
                }
            }
            m = m_new;
        }
    }

    float invl = 1.0f / l;
    #pragma unroll
    for (int d = 0; d < 32; d += 8) {
        bf16x8 ov;
        #pragma unroll
        for (int z = 0; z < 8; ++z) ov[z] = (__bf16)(o[d + z] * invl);
        *(bf16x8*)(vo + qrow + d) = ov;
    }
}

// ---------------------------------------------------------------- launch

extern "C" void kernel_launch(void* const* d_in, const int* in_sizes, int n_in,
                              void* d_out, int out_size, void* d_ws, size_t ws_size,
                              hipStream_t stream) {
    const float* x    = (const float*)d_in[0];
    const float* cosp = (const float*)d_in[1];
    const float* sinp = (const float*)d_in[2];
    const float* Wq   = (const float*)d_in[3];
    const float* bq   = (const float*)d_in[4];
    const float* Wkv  = (const float*)d_in[5];
    const float* bkv  = (const float*)d_in[6];
    const float* Wo   = (const float*)d_in[7];
    const float* bo   = (const float*)d_in[8];
    const int* causal = (const int*)d_in[9];
    float* out = (float*)d_out;

    const int B = 2, S = 2048, DIM = 2048;
    const int M = B * S;  // 4096

    // workspace layout (76 MB total)
    char* w = (char*)d_ws;
    __bf16* x16   = (__bf16*)w; w += (size_t)M * 2048 * 2;     // 16 MB
    __bf16* Wqt   = (__bf16*)w; w += (size_t)2048 * 2048 * 2;  //  8 MB
    __bf16* Wkvt  = (__bf16*)w; w += (size_t)1024 * 2048 * 2;  //  4 MB
    __bf16* Wot   = (__bf16*)w; w += (size_t)2048 * 2048 * 2;  //  8 MB
    __bf16* qbuf  = (__bf16*)w; w += (size_t)M * 2048 * 2;     // 16 MB
    __bf16* kvbuf = (__bf16*)w; w += (size_t)M * 1024 * 2;     //  8 MB
    __bf16* vobuf = (__bf16*)w; w += (size_t)M * 2048 * 2;     // 16 MB

    // 1. convert x to bf16
    f32_to_bf16_kernel<<<(M * 2048) / (256 * 8), 256, 0, stream>>>(x, x16, (size_t)M * 2048);
    // 2. transpose+convert weights: W[K][N] -> Wt[N][K] bf16
    transpose_to_bf16_kernel<<<dim3(2048 / 32, 2048 / 32), dim3(32, 8), 0, stream>>>(Wq, Wqt, 2048, 2048);
    transpose_to_bf16_kernel<<<dim3(1024 / 32, 2048 / 32), dim3(32, 8), 0, stream>>>(Wkv, Wkvt, 2048, 1024);
    transpose_to_bf16_kernel<<<dim3(2048 / 32, 2048 / 32), dim3(32, 8), 0, stream>>>(Wo, Wot, 2048, 2048);
    // 3. projections
    gemm_bt_bias_kernel<__bf16><<<dim3(M / BM, 2048 / BN), 256, 0, stream>>>(x16, Wqt, bq, qbuf, M, 2048, 2048);
    gemm_bt_bias_kernel<__bf16><<<dim3(M / BM, 1024 / BN), 256, 0, stream>>>(x16, Wkvt, bkv, kvbuf, M, 1024, 2048);
    // 4. RoPE on q (16 heads) and k half of kv (4 heads)
    {
        int totq = M * 16 * 64;
        rope_kernel<<<(totq + 255) / 256, 256, 0, stream>>>(qbuf, cosp, sinp, 16, 2048, S, totq);
        int totk = M * 4 * 64;
        rope_kernel<<<(totk + 255) / 256, 256, 0, stream>>>(kvbuf, cosp, sinp, 4, 1024, S, totk);
    }
    // 5. flash attention
    flash_attn_kernel<<<dim3(S / FA_BQ, 16, B), 256, 0, stream>>>(qbuf, kvbuf, vobuf, causal, B, S);
    // 6. output projection (fp32 out)
    gemm_bt_bias_kernel<float><<<dim3(M / BM, 2048 / BN), 256, 0, stream>>>(vobuf, Wot, bo, out, M, 2048, 2048);
}

// Round 2
// 588.377 us; speedup vs baseline: 3.0407x; 3.0407x over previous
//
#include <hip/hip_runtime.h>
#include <hip/hip_bf16.h>

typedef __bf16 bf16x8 __attribute__((ext_vector_type(8)));
typedef float  f32x4  __attribute__((ext_vector_type(4)));

// ---------------------------------------------------------------- converts

__global__ __launch_bounds__(256) void f32_to_bf16_kernel(
    const float* __restrict__ in, __bf16* __restrict__ out, size_t n) {
    size_t i = ((size_t)blockIdx.x * 256 + threadIdx.x) * 8;
    if (i >= n) return;
    float4 a = *(const float4*)(in + i);
    float4 b = *(const float4*)(in + i + 4);
    bf16x8 v;
    v[0] = (__bf16)a.x; v[1] = (__bf16)a.y; v[2] = (__bf16)a.z; v[3] = (__bf16)a.w;
    v[4] = (__bf16)b.x; v[5] = (__bf16)b.y; v[6] = (__bf16)b.z; v[7] = (__bf16)b.w;
    *(bf16x8*)(out + i) = v;
}

// W[K][N] fp32  ->  Wt[N][K] bf16   (32x32 LDS tile transpose)
__global__ __launch_bounds__(256) void transpose_to_bf16_kernel(
    const float* __restrict__ W, __bf16* __restrict__ Wt, int K, int N) {
    __shared__ float tile[32][33];
    int n0 = blockIdx.x * 32, k0 = blockIdx.y * 32;
    int tx = threadIdx.x, ty = threadIdx.y;  // 32 x 8
    #pragma unroll
    for (int i = 0; i < 32; i += 8)
        tile[ty + i][tx] = W[(size_t)(k0 + ty + i) * N + n0 + tx];
    __syncthreads();
    #pragma unroll
    for (int i = 0; i < 32; i += 8)
        Wt[(size_t)(n0 + ty + i) * K + k0 + tx] = (__bf16)tile[tx][ty + i];
}

// V half of kv [b*S+s][1024] (cols 512..1023) -> Vt[(b*4+kvh)*128 + d][S] bf16
__global__ __launch_bounds__(256) void transpose_v_kernel(
    const __bf16* __restrict__ kv, __bf16* __restrict__ vtg, int S) {
    __shared__ __bf16 tile[32][33];
    int s0 = blockIdx.x * 32, d0 = blockIdx.y * 32, z = blockIdx.z;  // z = b*4+kvh
    int b = z >> 2, kvh = z & 3;
    int tx = threadIdx.x, ty = threadIdx.y;  // 32 x 8
    #pragma unroll
    for (int i = 0; i < 32; i += 8)
        tile[ty + i][tx] = kv[((size_t)b * S + s0 + ty + i) * 1024 + 512 + kvh * 128 + d0 + tx];
    __syncthreads();
    #pragma unroll
    for (int i = 0; i < 32; i += 8)
        vtg[((size_t)z * 128 + d0 + ty + i) * S + s0 + tx] = tile[tx][ty + i];
}

// ---------------------------------------------------------------- GEMM
// C[M][N] = A[M][K](bf16) @ Bt[N][K](bf16)^T + bias[N],  fp32 accumulate.
#define BM 128
#define BN 128
#define BK 32

template <typename OutT>
__global__ __launch_bounds__(256) void gemm_bt_bias_kernel(
    const __bf16* __restrict__ A, const __bf16* __restrict__ Bt,
    const float* __restrict__ bias, OutT* __restrict__ C,
    int M, int N, int K) {
    __shared__ __bf16 As[BM][BK + 8];
    __shared__ __bf16 Bs[BN][BK + 8];
    int tid  = threadIdx.x;
    int bm   = blockIdx.x;
    int bn   = blockIdx.y;
    int wave = tid >> 6;
    int lane = tid & 63;
    int wm   = (wave >> 1) * 64;
    int wn   = (wave & 1) * 64;
    int quad = lane >> 4;
    int l16  = lane & 15;
    int arow = tid >> 2;
    int acol = (tid & 3) * 8;

    f32x4 acc[4][4];
    f32x4 zero = {0.f, 0.f, 0.f, 0.f};
    #pragma unroll
    for (int i = 0; i < 4; ++i)
        #pragma unroll
        for (int j = 0; j < 4; ++j) acc[i][j] = zero;

    const __bf16* Abase = A  + (size_t)(bm * BM) * K;
    const __bf16* Bbase = Bt + (size_t)(bn * BN) * K;

    for (int k0 = 0; k0 < K; k0 += BK) {
        if (k0) __syncthreads();
        #pragma unroll
        for (int it = 0; it < 2; ++it) {
            int r = arow + it * 64;
            *(uint4*)(&As[r][acol]) = *(const uint4*)(Abase + (size_t)r * K + k0 + acol);
            *(uint4*)(&Bs[r][acol]) = *(const uint4*)(Bbase + (size_t)r * K + k0 + acol);
        }
        __syncthreads();

        bf16x8 a_frag[4], b_frag[4];
        #pragma unroll
        for (int i = 0; i < 4; ++i)
            a_frag[i] = *(bf16x8*)(&As[wm + i * 16 + l16][quad * 8]);
        #pragma unroll
        for (int j = 0; j < 4; ++j)
            b_frag[j] = *(bf16x8*)(&Bs[wn + j * 16 + l16][quad * 8]);
        #pragma unroll
        for (int i = 0; i < 4; ++i)
            #pragma unroll
            for (int j = 0; j < 4; ++j)
                acc[i][j] = __builtin_amdgcn_mfma_f32_16x16x32_bf16(
                    a_frag[i], b_frag[j], acc[i][j], 0, 0, 0);
    }

    #pragma unroll
    for (int i = 0; i < 4; ++i) {
        int row = bm * BM + wm + i * 16 + quad * 4;
        #pragma unroll
        for (int j = 0; j < 4; ++j) {
            int col  = bn * BN + wn + j * 16 + l16;
            float bv = bias[col];
            #pragma unroll
            for (int r = 0; r < 4; ++r)
                C[(size_t)(row + r) * N + col] = (OutT)(acc[i][j][r] + bv);
        }
    }
}

// ---------------------------------------------------------------- RoPE (in-place, bf16)
__global__ __launch_bounds__(256) void rope_kernel(
    __bf16* __restrict__ buf, const float* __restrict__ cosp,
    const float* __restrict__ sinp, int heads, int rowstride, int S, int total) {
    int idx = blockIdx.x * 256 + threadIdx.x;
    if (idx >= total) return;
    int d  = idx & 63;
    int t2 = idx >> 6;
    int h  = t2 % heads;
    int r  = t2 / heads;
    int s  = r & (S - 1);
    size_t base = (size_t)r * rowstride + h * 128;
    float x1 = (float)buf[base + d];
    float x2 = (float)buf[base + d + 64];
    float c  = cosp[s * 64 + d];
    float sn = sinp[s * 64 + d];
    buf[base + d]      = (__bf16)(x1 * c - x2 * sn);
    buf[base + d + 64] = (__bf16)(x1 * sn + x2 * c);
}

// ---------------------------------------------------------------- MFMA flash attention
// 4 waves/block. Q-tile 64 rows (16/wave), K-tile 64 keys.
// QK^T and PV via mfma_f32_16x16x32_bf16; online softmax in VALU.
// C/D layout (HW-verified m89/m91): row = quad*4+reg, col = lane&15.
// A/B operand layout: lane holds [idx = lane&15][k = quad*8+j].
#define FB_K   64
#define KS_STR 136   // 64 keys x 128 dims + 8 pad  (16B-aligned rows, banks spread 4*((l16+quad)%8))
#define VT_STR 72    // 128 dims x 64 keys + 8 pad
#define PS_STR 72    // per-wave P: 16 q-rows x 64 keys + 8 pad

__global__ __launch_bounds__(256) void flash_mfma_kernel(
    const __bf16* __restrict__ q,    // [B*S][2048], rope applied
    const __bf16* __restrict__ kv,   // [B*S][1024]: k cols 0..511 (roped)
    const __bf16* __restrict__ vtg,  // [(b*4+kvh)*128 + d][S]  (V transposed)
    __bf16* __restrict__ vo,         // [B*S][2048]
    const int* __restrict__ causal_p, int B, int S) {
    __shared__ __bf16 Ks[64 * KS_STR];
    __shared__ __bf16 Vt[128 * VT_STR];
    __shared__ __bf16 Ps[4 * 16 * PS_STR];

    int tid  = threadIdx.x;
    int wave = tid >> 6;
    int lane = tid & 63;
    int quad = lane >> 4;
    int l16  = lane & 15;
    int qt   = (gridDim.x - 1) - blockIdx.x;  // reversed: heavy (causal) blocks first
    int h    = blockIdx.y;
    int b    = blockIdx.z;
    int kvh  = h >> 2;
    int q0   = qt * 64;
    int causal = causal_p[0];
    const float SCALE = 0.08838834764831845f;  // 1/sqrt(128)

    // Q A-frags: wave rows q0+wave*16 .. +15; lane holds row l16, dims kc*32+quad*8..+7
    bf16x8 a_frag[4];
    {
        size_t qbase = ((size_t)b * S + q0 + wave * 16 + l16) * 2048 + h * 128 + quad * 8;
        #pragma unroll
        for (int kc = 0; kc < 4; ++kc)
            a_frag[kc] = *(const bf16x8*)(q + qbase + kc * 32);
    }

    f32x4 o_acc[8];
    f32x4 zero4 = {0.f, 0.f, 0.f, 0.f};
    #pragma unroll
    for (int dt = 0; dt < 8; ++dt) o_acc[dt] = zero4;
    float m_[4], l_[4];
    #pragma unroll
    for (int r = 0; r < 4; ++r) { m_[r] = -1e30f; l_[r] = 0.f; }
    int qrow_base = q0 + wave * 16 + quad * 4;

    const __bf16* kbase0 = kv + ((size_t)b * S) * 1024 + kvh * 128;
    const __bf16* vbase0 = vtg + ((size_t)(b * 4 + kvh) * 128) * S;

    int ntiles = causal ? (qt + 1) : (S / FB_K);
    for (int t = 0; t < ntiles; ++t) {
        int j0 = t * FB_K;
        __syncthreads();
        // stage K (key-major) and Vt (dim-major), fully vectorized
        #pragma unroll
        for (int it = 0; it < 4; ++it) {
            int g = it * 256 + tid;
            int key = g >> 4, dg = (g & 15) * 8;
            *(bf16x8*)&Ks[key * KS_STR + dg] =
                *(const bf16x8*)(kbase0 + (size_t)(j0 + key) * 1024 + dg);
        }
        #pragma unroll
        for (int it = 0; it < 4; ++it) {
            int g = it * 256 + tid;
            int d = g >> 3, kg = (g & 7) * 8;
            *(bf16x8*)&Vt[d * VT_STR + kg] =
                *(const bf16x8*)(vbase0 + (size_t)d * S + j0 + kg);
        }
        __syncthreads();

        // S = Q @ K^T  (rows=q, cols=keys)
        f32x4 s_t[4];
        #pragma unroll
        for (int jt = 0; jt < 4; ++jt) s_t[jt] = zero4;
        #pragma unroll
        for (int jt = 0; jt < 4; ++jt)
            #pragma unroll
            for (int kc = 0; kc < 4; ++kc) {
                bf16x8 bf = *(bf16x8*)&Ks[(jt * 16 + l16) * KS_STR + kc * 32 + quad * 8];
                s_t[jt] = __builtin_amdgcn_mfma_f32_16x16x32_bf16(a_frag[kc], bf, s_t[jt], 0, 0, 0);
            }

        // scale + causal mask (only diagonal tile needs it)
        int diag = causal && (t == qt);
        #pragma unroll
        for (int jt = 0; jt < 4; ++jt)
            #pragma unroll
            for (int r = 0; r < 4; ++r) {
                float sv = s_t[jt][r] * SCALE;
                if (diag && (j0 + jt * 16 + l16 > qrow_base + r)) sv = -1e30f;
                s_t[jt][r] = sv;
            }

        // online softmax per q-row (state replicated across the 16 l16 lanes)
        float alpha[4];
        #pragma unroll
        for (int r = 0; r < 4; ++r) {
            float v = fmaxf(fmaxf(s_t[0][r], s_t[1][r]), fmaxf(s_t[2][r], s_t[3][r]));
            v = fmaxf(v, __shfl_xor(v, 1));
            v = fmaxf(v, __shfl_xor(v, 2));
            v = fmaxf(v, __shfl_xor(v, 4));
            v = fmaxf(v, __shfl_xor(v, 8));
            float m_new = fmaxf(m_[r], v);
            float al = __expf(m_[r] - m_new);
            m_[r] = m_new;
            alpha[r] = al;
            float rs = 0.f;
            #pragma unroll
            for (int jt = 0; jt < 4; ++jt) {
                float p = __expf(s_t[jt][r] - m_new);
                s_t[jt][r] = p;
                rs += p;
            }
            rs += __shfl_xor(rs, 1);
            rs += __shfl_xor(rs, 2);
            rs += __shfl_xor(rs, 4);
            rs += __shfl_xor(rs, 8);
            l_[r] = l_[r] * al + rs;
        }
        #pragma unroll
        for (int dt = 0; dt < 8; ++dt)
            #pragma unroll
            for (int r = 0; r < 4; ++r) o_acc[dt][r] *= alpha[r];

        // P (C-layout) -> LDS -> A-layout (per-wave private buffer, no barrier needed)
        #pragma unroll
        for (int jt = 0; jt < 4; ++jt)
            #pragma unroll
            for (int r = 0; r < 4; ++r)
                Ps[(wave * 16 + quad * 4 + r) * PS_STR + jt * 16 + l16] = (__bf16)s_t[jt][r];

        bf16x8 p_frag[2];
        p_frag[0] = *(bf16x8*)&Ps[(wave * 16 + l16) * PS_STR + quad * 8];
        p_frag[1] = *(bf16x8*)&Ps[(wave * 16 + l16) * PS_STR + 32 + quad * 8];
        #pragma unroll
        for (int dt = 0; dt < 8; ++dt) {
            bf16x8 v0 = *(bf16x8*)&Vt[(dt * 16 + l16) * VT_STR + quad * 8];
            bf16x8 v1 = *(bf16x8*)&Vt[(dt * 16 + l16) * VT_STR + 32 + quad * 8];
            o_acc[dt] = __builtin_amdgcn_mfma_f32_16x16x32_bf16(p_frag[0], v0, o_acc[dt], 0, 0, 0);
            o_acc[dt] = __builtin_amdgcn_mfma_f32_16x16x32_bf16(p_frag[1], v1, o_acc[dt], 0, 0, 0);
        }
    }

    float invl[4];
    #pragma unroll
    for (int r = 0; r < 4; ++r) invl[r] = 1.f / l_[r];
    size_t obase = ((size_t)b * S + q0 + wave * 16 + quad * 4) * 2048 + h * 128 + l16;
    #pragma unroll
    for (int dt = 0; dt < 8; ++dt)
        #pragma unroll
        for (int r = 0; r < 4; ++r)
            vo[obase + (size_t)r * 2048 + dt * 16] = (__bf16)(o_acc[dt][r] * invl[r]);
}

// ---------------------------------------------------------------- launch

extern "C" void kernel_launch(void* const* d_in, const int* in_sizes, int n_in,
                              void* d_out, int out_size, void* d_ws, size_t ws_size,
                              hipStream_t stream) {
    const float* x    = (const float*)d_in[0];
    const float* cosp = (const float*)d_in[1];
    const float* sinp = (const float*)d_in[2];
    const float* Wq   = (const float*)d_in[3];
    const float* bq   = (const float*)d_in[4];
    const float* Wkv  = (const float*)d_in[5];
    const float* bkv  = (const float*)d_in[6];
    const float* Wo   = (const float*)d_in[7];
    const float* bo   = (const float*)d_in[8];
    const int* causal = (const int*)d_in[9];
    float* out = (float*)d_out;

    const int B = 2, S = 2048;
    const int M = B * S;  // 4096

    // workspace layout (76 MB)
    char* w = (char*)d_ws;
    __bf16* x16   = (__bf16*)w; w += (size_t)M * 2048 * 2;     // 16 MB
    __bf16* Wqt   = (__bf16*)w; w += (size_t)2048 * 2048 * 2;  //  8 MB
    __bf16* Wkvt  = (__bf16*)w; w += (size_t)1024 * 2048 * 2;  //  4 MB
    __bf16* Wot   = (__bf16*)w; w += (size_t)2048 * 2048 * 2;  //  8 MB
    __bf16* qbuf  = (__bf16*)w; w += (size_t)M * 2048 * 2;     // 16 MB
    __bf16* kvbuf = (__bf16*)w; w += (size_t)M * 1024 * 2;     //  8 MB
    __bf16* vobuf = (__bf16*)w; w += (size_t)M * 2048 * 2;     // 16 MB
    __bf16* vtg   = Wqt;  // alias: Wqt dead after Q GEMM; vtg needs 4 MB <= 8 MB

    f32_to_bf16_kernel<<<(M * 2048) / (256 * 8), 256, 0, stream>>>(x, x16, (size_t)M * 2048);
    transpose_to_bf16_kernel<<<dim3(2048 / 32, 2048 / 32), dim3(32, 8), 0, stream>>>(Wq, Wqt, 2048, 2048);
    transpose_to_bf16_kernel<<<dim3(1024 / 32, 2048 / 32), dim3(32, 8), 0, stream>>>(Wkv, Wkvt, 2048, 1024);
    transpose_to_bf16_kernel<<<dim3(2048 / 32, 2048 / 32), dim3(32, 8), 0, stream>>>(Wo, Wot, 2048, 2048);
    gemm_bt_bias_kernel<__bf16><<<dim3(M / BM, 2048 / BN), 256, 0, stream>>>(x16, Wqt, bq, qbuf, M, 2048, 2048);
    gemm_bt_bias_kernel<__bf16><<<dim3(M / BM, 1024 / BN), 256, 0, stream>>>(x16, Wkvt, bkv, kvbuf, M, 1024, 2048);
    {
        int totq = M * 16 * 64;
        rope_kernel<<<(totq + 255) / 256, 256, 0, stream>>>(qbuf, cosp, sinp, 16, 2048, S, totq);
        int totk = M * 4 * 64;
        rope_kernel<<<(totk + 255) / 256, 256, 0, stream>>>(kvbuf, cosp, sinp, 4, 1024, S, totk);
    }
    // V -> dim-major global layout (vtg aliases Wqt, which is dead by now)
    transpose_v_kernel<<<dim3(S / 32, 128 / 32, B * 4), dim3(32, 8), 0, stream>>>(kvbuf, vtg, S);
    flash_mfma_kernel<<<dim3(S / 64, 16, B), 256, 0, stream>>>(qbuf, kvbuf, vtg, vobuf, causal, B, S);
    gemm_bt_bias_kernel<float><<<dim3(M / BM, 2048 / BN), 256, 0, stream>>>(vobuf, Wot, bo, out, M, 2048, 2048);
}

// Round 3
// 583.307 us; speedup vs baseline: 3.0672x; 1.0087x over previous
//
#include <hip/hip_runtime.h>
#include <hip/hip_bf16.h>

typedef __bf16 bf16x8 __attribute__((ext_vector_type(8)));
typedef float  f32x4  __attribute__((ext_vector_type(4)));

// ---------------------------------------------------------------- converts

__global__ __launch_bounds__(256) void f32_to_bf16_kernel(
    const float* __restrict__ in, __bf16* __restrict__ out, size_t n) {
    size_t i = ((size_t)blockIdx.x * 256 + threadIdx.x) * 8;
    if (i >= n) return;
    float4 a = *(const float4*)(in + i);
    float4 b = *(const float4*)(in + i + 4);
    bf16x8 v;
    v[0] = (__bf16)a.x; v[1] = (__bf16)a.y; v[2] = (__bf16)a.z; v[3] = (__bf16)a.w;
    v[4] = (__bf16)b.x; v[5] = (__bf16)b.y; v[6] = (__bf16)b.z; v[7] = (__bf16)b.w;
    *(bf16x8*)(out + i) = v;
}

// W[K][N] fp32  ->  Wt[N][K] bf16   (32x32 LDS tile transpose)
__global__ __launch_bounds__(256) void transpose_to_bf16_kernel(
    const float* __restrict__ W, __bf16* __restrict__ Wt, int K, int N) {
    __shared__ float tile[32][33];
    int n0 = blockIdx.x * 32, k0 = blockIdx.y * 32;
    int tx = threadIdx.x, ty = threadIdx.y;  // 32 x 8
    #pragma unroll
    for (int i = 0; i < 32; i += 8)
        tile[ty + i][tx] = W[(size_t)(k0 + ty + i) * N + n0 + tx];
    __syncthreads();
    #pragma unroll
    for (int i = 0; i < 32; i += 8)
        Wt[(size_t)(n0 + ty + i) * K + k0 + tx] = (__bf16)tile[tx][ty + i];
}

// V half of kv [b*S+s][1024] (cols 512..1023) -> Vt[(b*4+kvh)*128 + d][S] bf16
__global__ __launch_bounds__(256) void transpose_v_kernel(
    const __bf16* __restrict__ kv, __bf16* __restrict__ vtg, int S) {
    __shared__ __bf16 tile[32][33];
    int s0 = blockIdx.x * 32, d0 = blockIdx.y * 32, z = blockIdx.z;  // z = b*4+kvh
    int b = z >> 2, kvh = z & 3;
    int tx = threadIdx.x, ty = threadIdx.y;  // 32 x 8
    #pragma unroll
    for (int i = 0; i < 32; i += 8)
        tile[ty + i][tx] = kv[((size_t)b * S + s0 + ty + i) * 1024 + 512 + kvh * 128 + d0 + tx];
    __syncthreads();
    #pragma unroll
    for (int i = 0; i < 32; i += 8)
        vtg[((size_t)z * 128 + d0 + ty + i) * S + s0 + tx] = tile[tx][ty + i];
}

// ---------------------------------------------------------------- GEMM
// C[M][N] = A[M][K](bf16) @ Bt[N][K](bf16)^T + bias[N],  fp32 accumulate.
#define BM 128
#define BN 128
#define BK 32

template <typename OutT>
__global__ __launch_bounds__(256) void gemm_bt_bias_kernel(
    const __bf16* __restrict__ A, const __bf16* __restrict__ Bt,
    const float* __restrict__ bias, OutT* __restrict__ C,
    int M, int N, int K) {
    __shared__ __bf16 As[BM][BK + 8];
    __shared__ __bf16 Bs[BN][BK + 8];
    int tid  = threadIdx.x;
    int bm   = blockIdx.x;
    int bn   = blockIdx.y;
    int wave = tid >> 6;
    int lane = tid & 63;
    int wm   = (wave >> 1) * 64;
    int wn   = (wave & 1) * 64;
    int quad = lane >> 4;
    int l16  = lane & 15;
    int arow = tid >> 2;
    int acol = (tid & 3) * 8;

    f32x4 acc[4][4];
    f32x4 zero = {0.f, 0.f, 0.f, 0.f};
    #pragma unroll
    for (int i = 0; i < 4; ++i)
        #pragma unroll
        for (int j = 0; j < 4; ++j) acc[i][j] = zero;

    const __bf16* Abase = A  + (size_t)(bm * BM) * K;
    const __bf16* Bbase = Bt + (size_t)(bn * BN) * K;

    for (int k0 = 0; k0 < K; k0 += BK) {
        if (k0) __syncthreads();
        #pragma unroll
        for (int it = 0; it < 2; ++it) {
            int r = arow + it * 64;
            *(uint4*)(&As[r][acol]) = *(const uint4*)(Abase + (size_t)r * K + k0 + acol);
            *(uint4*)(&Bs[r][acol]) = *(const uint4*)(Bbase + (size_t)r * K + k0 + acol);
        }
        __syncthreads();

        bf16x8 a_frag[4], b_frag[4];
        #pragma unroll
        for (int i = 0; i < 4; ++i)
            a_frag[i] = *(bf16x8*)(&As[wm + i * 16 + l16][quad * 8]);
        #pragma unroll
        for (int j = 0; j < 4; ++j)
            b_frag[j] = *(bf16x8*)(&Bs[wn + j * 16 + l16][quad * 8]);
        #pragma unroll
        for (int i = 0; i < 4; ++i)
            #pragma unroll
            for (int j = 0; j < 4; ++j)
                acc[i][j] = __builtin_amdgcn_mfma_f32_16x16x32_bf16(
                    a_frag[i], b_frag[j], acc[i][j], 0, 0, 0);
    }

    #pragma unroll
    for (int i = 0; i < 4; ++i) {
        int row = bm * BM + wm + i * 16 + quad * 4;
        #pragma unroll
        for (int j = 0; j < 4; ++j) {
            int col  = bn * BN + wn + j * 16 + l16;
            float bv = bias[col];
            #pragma unroll
            for (int r = 0; r < 4; ++r)
                C[(size_t)(row + r) * N + col] = (OutT)(acc[i][j][r] + bv);
        }
    }
}

// ---------------------------------------------------------------- RoPE (in-place, bf16)
__global__ __launch_bounds__(256) void rope_kernel(
    __bf16* __restrict__ buf, const float* __restrict__ cosp,
    const float* __restrict__ sinp, int heads, int rowstride, int S, int total) {
    int idx = blockIdx.x * 256 + threadIdx.x;
    if (idx >= total) return;
    int d  = idx & 63;
    int t2 = idx >> 6;
    int h  = t2 % heads;
    int r  = t2 / heads;
    int s  = r & (S - 1);
    size_t base = (size_t)r * rowstride + h * 128;
    float x1 = (float)buf[base + d];
    float x2 = (float)buf[base + d + 64];
    float c  = cosp[s * 64 + d];
    float sn = sinp[s * 64 + d];
    buf[base + d]      = (__bf16)(x1 * c - x2 * sn);
    buf[base + d + 64] = (__bf16)(x1 * sn + x2 * c);
}

// ---------------------------------------------------------------- MFMA flash attention (barrier-free)
// 4 waves/block, Q-tile 128 rows: wave w owns rows q0 + mt*64 + w*16 (mt=0,1).
// K and V frags are read DIRECTLY from global in B-operand layout
// (K key-major, vtg dim-major): lane l16 -> row, quad*8 -> 16B contiguous.
// No __syncthreads anywhere; only LDS use is the per-wave P C->A transform.
// C/D layout (HW-verified m89/m91): row = quad*4+reg, col = lane&15.
#define FB_K   64
#define PS_STR 72    // 64 keys + 8 pad (banks spread 4*((l16+quad)%8))

__global__ __launch_bounds__(256) void flash_mfma_kernel(
    const __bf16* __restrict__ q,    // [B*S][2048], rope applied
    const __bf16* __restrict__ kv,   // [B*S][1024]: k cols 0..511 (roped)
    const __bf16* __restrict__ vtg,  // [(b*4+kvh)*128 + d][S]  (V transposed)
    __bf16* __restrict__ vo,         // [B*S][2048]
    const int* __restrict__ causal_p, int S) {
    __shared__ __bf16 Ps[4 * 32 * PS_STR];  // 4 waves x 32 q-rows x 64 keys

    int tid  = threadIdx.x;
    int wave = tid >> 6;
    int lane = tid & 63;
    int quad = lane >> 4;
    int l16  = lane & 15;
    // XCD swizzle: id%8 -> (b,kvh) so each XCD's L2 caches one K/V set.
    int id   = blockIdx.x;
    int xcd  = id & 7;
    int b    = xcd >> 2;
    int kvh  = xcd & 3;
    int rest = id >> 3;
    int qt   = 15 - (rest & 15);          // heavy (causal) blocks first
    int h    = kvh * 4 + (rest >> 4);
    int q0   = qt * 128;
    int causal = causal_p[0];
    const float SCALE = 0.08838834764831845f;  // 1/sqrt(128)

    // Q A-frags: lane holds row l16 of its 16-row tile, dims kc*32+quad*8..+7
    bf16x8 a_frag[2][4];
    #pragma unroll
    for (int mt = 0; mt < 2; ++mt) {
        size_t qbase = ((size_t)b * S + q0 + mt * 64 + wave * 16 + l16) * 2048
                       + h * 128 + quad * 8;
        #pragma unroll
        for (int kc = 0; kc < 4; ++kc)
            a_frag[mt][kc] = *(const bf16x8*)(q + qbase + kc * 32);
    }

    f32x4 o_acc[2][8];
    f32x4 zero4 = {0.f, 0.f, 0.f, 0.f};
    #pragma unroll
    for (int mt = 0; mt < 2; ++mt)
        #pragma unroll
        for (int dt = 0; dt < 8; ++dt) o_acc[mt][dt] = zero4;
    float m_[2][4], l_[2][4];
    #pragma unroll
    for (int mt = 0; mt < 2; ++mt)
        #pragma unroll
        for (int r = 0; r < 4; ++r) { m_[mt][r] = -1e30f; l_[mt][r] = 0.f; }

    const __bf16* kbase = kv  + ((size_t)b * S) * 1024 + kvh * 128;
    const __bf16* vbase = vtg + ((size_t)(b * 4 + kvh) * 128) * S;

    int ntiles = causal ? (2 * qt + 2) : (S / FB_K);
    for (int t = 0; t < ntiles; ++t) {
        int j0 = t * FB_K;

        // ---- S = Q @ K^T, K frags straight from global
        f32x4 s_t[2][4];
        #pragma unroll
        for (int mt = 0; mt < 2; ++mt)
            #pragma unroll
            for (int jt = 0; jt < 4; ++jt) s_t[mt][jt] = zero4;
        #pragma unroll
        for (int jt = 0; jt < 4; ++jt) {
            const __bf16* kp = kbase + (size_t)(j0 + jt * 16 + l16) * 1024 + quad * 8;
            bf16x8 kf[4];
            #pragma unroll
            for (int kc = 0; kc < 4; ++kc) kf[kc] = *(const bf16x8*)(kp + kc * 32);
            #pragma unroll
            for (int mt = 0; mt < 2; ++mt)
                #pragma unroll
                for (int kc = 0; kc < 4; ++kc)
                    s_t[mt][jt] = __builtin_amdgcn_mfma_f32_16x16x32_bf16(
                        a_frag[mt][kc], kf[kc], s_t[mt][jt], 0, 0, 0);
        }

        // ---- scale + causal mask (only the last two tiles touch the diagonal)
        int diag = causal && (t >= 2 * qt);
        #pragma unroll
        for (int mt = 0; mt < 2; ++mt) {
            int qrow = q0 + mt * 64 + wave * 16 + quad * 4;
            #pragma unroll
            for (int jt = 0; jt < 4; ++jt)
                #pragma unroll
                for (int r = 0; r < 4; ++r) {
                    float sv = s_t[mt][jt][r] * SCALE;
                    if (diag && (j0 + jt * 16 + l16 > qrow + r)) sv = -1e30f;
                    s_t[mt][jt][r] = sv;
                }
        }

        // ---- online softmax per q-row (state replicated over the 16 l16 lanes)
        #pragma unroll
        for (int mt = 0; mt < 2; ++mt) {
            float alpha[4];
            #pragma unroll
            for (int r = 0; r < 4; ++r) {
                float v = fmaxf(fmaxf(s_t[mt][0][r], s_t[mt][1][r]),
                                fmaxf(s_t[mt][2][r], s_t[mt][3][r]));
                v = fmaxf(v, __shfl_xor(v, 1));
                v = fmaxf(v, __shfl_xor(v, 2));
                v = fmaxf(v, __shfl_xor(v, 4));
                v = fmaxf(v, __shfl_xor(v, 8));
                float m_new = fmaxf(m_[mt][r], v);
                float al = __expf(m_[mt][r] - m_new);
                m_[mt][r] = m_new;
                alpha[r] = al;
                float rs = 0.f;
                #pragma unroll
                for (int jt = 0; jt < 4; ++jt) {
                    float p = __expf(s_t[mt][jt][r] - m_new);
                    s_t[mt][jt][r] = p;
                    rs += p;
                }
                rs += __shfl_xor(rs, 1);
                rs += __shfl_xor(rs, 2);
                rs += __shfl_xor(rs, 4);
                rs += __shfl_xor(rs, 8);
                l_[mt][r] = l_[mt][r] * al + rs;
            }
            #pragma unroll
            for (int dt = 0; dt < 8; ++dt)
                #pragma unroll
                for (int r = 0; r < 4; ++r) o_acc[mt][dt][r] *= alpha[r];
            // P (C-layout) -> per-wave LDS (no barrier: private region)
            #pragma unroll
            for (int jt = 0; jt < 4; ++jt)
                #pragma unroll
                for (int r = 0; r < 4; ++r)
                    Ps[(wave * 32 + mt * 16 + quad * 4 + r) * PS_STR + jt * 16 + l16] =
                        (__bf16)s_t[mt][jt][r];
        }

        // ---- P A-frags back from LDS, V frags straight from global (dim-major)
        bf16x8 p_frag[2][2];
        #pragma unroll
        for (int mt = 0; mt < 2; ++mt) {
            p_frag[mt][0] = *(bf16x8*)&Ps[(wave * 32 + mt * 16 + l16) * PS_STR + quad * 8];
            p_frag[mt][1] = *(bf16x8*)&Ps[(wave * 32 + mt * 16 + l16) * PS_STR + 32 + quad * 8];
        }
        #pragma unroll
        for (int dt = 0; dt < 8; ++dt) {
            const __bf16* vp = vbase + (size_t)(dt * 16 + l16) * S + j0 + quad * 8;
            bf16x8 v0 = *(const bf16x8*)(vp);
            bf16x8 v1 = *(const bf16x8*)(vp + 32);
            #pragma unroll
            for (int mt = 0; mt < 2; ++mt) {
                o_acc[mt][dt] = __builtin_amdgcn_mfma_f32_16x16x32_bf16(
                    p_frag[mt][0], v0, o_acc[mt][dt], 0, 0, 0);
                o_acc[mt][dt] = __builtin_amdgcn_mfma_f32_16x16x32_bf16(
                    p_frag[mt][1], v1, o_acc[mt][dt], 0, 0, 0);
            }
        }
    }

    #pragma unroll
    for (int mt = 0; mt < 2; ++mt) {
        float invl[4];
        #pragma unroll
        for (int r = 0; r < 4; ++r) invl[r] = 1.f / l_[mt][r];
        size_t obase = ((size_t)b * S + q0 + mt * 64 + wave * 16 + quad * 4) * 2048
                       + h * 128 + l16;
        #pragma unroll
        for (int dt = 0; dt < 8; ++dt)
            #pragma unroll
            for (int r = 0; r < 4; ++r)
                vo[obase + (size_t)r * 2048 + dt * 16] = (__bf16)(o_acc[mt][dt][r] * invl[r]);
    }
}

// ---------------------------------------------------------------- launch

extern "C" void kernel_launch(void* const* d_in, const int* in_sizes, int n_in,
                              void* d_out, int out_size, void* d_ws, size_t ws_size,
                              hipStream_t stream) {
    const float* x    = (const float*)d_in[0];
    const float* cosp = (const float*)d_in[1];
    const float* sinp = (const float*)d_in[2];
    const float* Wq   = (const float*)d_in[3];
    const float* bq   = (const float*)d_in[4];
    const float* Wkv  = (const float*)d_in[5];
    const float* bkv  = (const float*)d_in[6];
    const float* Wo   = (const float*)d_in[7];
    const float* bo   = (const float*)d_in[8];
    const int* causal = (const int*)d_in[9];
    float* out = (float*)d_out;

    const int B = 2, S = 2048;
    const int M = B * S;  // 4096

    // workspace layout (76 MB)
    char* w = (char*)d_ws;
    __bf16* x16   = (__bf16*)w; w += (size_t)M * 2048 * 2;     // 16 MB
    __bf16* Wqt   = (__bf16*)w; w += (size_t)2048 * 2048 * 2;  //  8 MB
    __bf16* Wkvt  = (__bf16*)w; w += (size_t)1024 * 2048 * 2;  //  4 MB
    __bf16* Wot   = (__bf16*)w; w += (size_t)2048 * 2048 * 2;  //  8 MB
    __bf16* qbuf  = (__bf16*)w; w += (size_t)M * 2048 * 2;     // 16 MB
    __bf16* kvbuf = (__bf16*)w; w += (size_t)M * 1024 * 2;     //  8 MB
    __bf16* vobuf = (__bf16*)w; w += (size_t)M * 2048 * 2;     // 16 MB
    __bf16* vtg   = Wqt;  // alias: Wqt dead after Q GEMM; vtg needs 4 MB <= 8 MB

    f32_to_bf16_kernel<<<(M * 2048) / (256 * 8), 256, 0, stream>>>(x, x16, (size_t)M * 2048);
    transpose_to_bf16_kernel<<<dim3(2048 / 32, 2048 / 32), dim3(32, 8), 0, stream>>>(Wq, Wqt, 2048, 2048);
    transpose_to_bf16_kernel<<<dim3(1024 / 32, 2048 / 32), dim3(32, 8), 0, stream>>>(Wkv, Wkvt, 2048, 1024);
    transpose_to_bf16_kernel<<<dim3(2048 / 32, 2048 / 32), dim3(32, 8), 0, stream>>>(Wo, Wot, 2048, 2048);
    gemm_bt_bias_kernel<__bf16><<<dim3(M / BM, 2048 / BN), 256, 0, stream>>>(x16, Wqt, bq, qbuf, M, 2048, 2048);
    gemm_bt_bias_kernel<__bf16><<<dim3(M / BM, 1024 / BN), 256, 0, stream>>>(x16, Wkvt, bkv, kvbuf, M, 1024, 2048);
    {
        int totq = M * 16 * 64;
        rope_kernel<<<(totq + 255) / 256, 256, 0, stream>>>(qbuf, cosp, sinp, 16, 2048, S, totq);
        int totk = M * 4 * 64;
        rope_kernel<<<(totk + 255) / 256, 256, 0, stream>>>(kvbuf, cosp, sinp, 4, 1024, S, totk);
    }
    transpose_v_kernel<<<dim3(S / 32, 128 / 32, B * 4), dim3(32, 8), 0, stream>>>(kvbuf, vtg, S);
    // 512 blocks: id%8 -> (b,kvh) XCD affinity; qt reversed so heavy blocks go first
    flash_mfma_kernel<<<dim3(512), 256, 0, stream>>>(qbuf, kvbuf, vtg, vobuf, causal, S);
    gemm_bt_bias_kernel<float><<<dim3(M / BM, 2048 / BN), 256, 0, stream>>>(vobuf, Wot, bo, out, M, 2048, 2048);
}

// Round 4
// 463.934 us; speedup vs baseline: 3.8564x; 1.2573x over previous
//
#include <hip/hip_runtime.h>
#include <hip/hip_bf16.h>

typedef __bf16 bf16x8 __attribute__((ext_vector_type(8)));
typedef float  f32x4  __attribute__((ext_vector_type(4)));
typedef unsigned int u32;

// async global->LDS, 16B/lane; LDS dest = wave-uniform base + lane*16 (m97/m104)
#define GLD_LDS16(gp, lp) __builtin_amdgcn_global_load_lds( \
    (const __attribute__((address_space(1))) u32*)(gp), \
    (__attribute__((address_space(3))) u32*)(lp), 16, 0, 0)

// DPP cyclic rotate within 16-lane rows (row_ror:N = 0x120|N) — VALU-pipe cross-lane
template<int CTRL>
__device__ __forceinline__ float dpp_rot(float x) {
    int y = __builtin_amdgcn_update_dpp(__float_as_int(x), __float_as_int(x),
                                        CTRL, 0xF, 0xF, false);
    return __int_as_float(y);
}
__device__ __forceinline__ float rowmax16(float x) {
    x = fmaxf(x, dpp_rot<0x121>(x));
    x = fmaxf(x, dpp_rot<0x122>(x));
    x = fmaxf(x, dpp_rot<0x124>(x));
    x = fmaxf(x, dpp_rot<0x128>(x));
    return x;
}
__device__ __forceinline__ float rowsum16(float x) {
    x += dpp_rot<0x121>(x);
    x += dpp_rot<0x122>(x);
    x += dpp_rot<0x124>(x);
    x += dpp_rot<0x128>(x);
    return x;
}

// ---------------------------------------------------------------- converts

__global__ __launch_bounds__(256) void f32_to_bf16_kernel(
    const float* __restrict__ in, __bf16* __restrict__ out, size_t n) {
    size_t i = ((size_t)blockIdx.x * 256 + threadIdx.x) * 8;
    if (i >= n) return;
    float4 a = *(const float4*)(in + i);
    float4 b = *(const float4*)(in + i + 4);
    bf16x8 v;
    v[0] = (__bf16)a.x; v[1] = (__bf16)a.y; v[2] = (__bf16)a.z; v[3] = (__bf16)a.w;
    v[4] = (__bf16)b.x; v[5] = (__bf16)b.y; v[6] = (__bf16)b.z; v[7] = (__bf16)b.w;
    *(bf16x8*)(out + i) = v;
}

// W[K][N] fp32  ->  Wt[N][K] bf16   (32x32 LDS tile transpose)
__global__ __launch_bounds__(256) void transpose_to_bf16_kernel(
    const float* __restrict__ W, __bf16* __restrict__ Wt, int K, int N) {
    __shared__ float tile[32][33];
    int n0 = blockIdx.x * 32, k0 = blockIdx.y * 32;
    int tx = threadIdx.x, ty = threadIdx.y;  // 32 x 8
    #pragma unroll
    for (int i = 0; i < 32; i += 8)
        tile[ty + i][tx] = W[(size_t)(k0 + ty + i) * N + n0 + tx];
    __syncthreads();
    #pragma unroll
    for (int i = 0; i < 32; i += 8)
        Wt[(size_t)(n0 + ty + i) * K + k0 + tx] = (__bf16)tile[tx][ty + i];
}

// V half of kv [b*S+s][1024] (cols 512..1023) -> Vt[(b*4+kvh)*128 + d][S] bf16
__global__ __launch_bounds__(256) void transpose_v_kernel(
    const __bf16* __restrict__ kv, __bf16* __restrict__ vtg, int S) {
    __shared__ __bf16 tile[32][33];
    int s0 = blockIdx.x * 32, d0 = blockIdx.y * 32, z = blockIdx.z;  // z = b*4+kvh
    int b = z >> 2, kvh = z & 3;
    int tx = threadIdx.x, ty = threadIdx.y;  // 32 x 8
    #pragma unroll
    for (int i = 0; i < 32; i += 8)
        tile[ty + i][tx] = kv[((size_t)b * S + s0 + ty + i) * 1024 + 512 + kvh * 128 + d0 + tx];
    __syncthreads();
    #pragma unroll
    for (int i = 0; i < 32; i += 8)
        vtg[((size_t)z * 128 + d0 + ty + i) * S + s0 + tx] = tile[tx][ty + i];
}

// ---------------------------------------------------------------- GEMM (m97 pattern)
// C[M][N] = A[M][K](bf16) @ Bt[N][K](bf16)^T + bias[N], fp32 accumulate.
// Staging via global_load_lds width=16 into UNPADDED LDS (DMA requires
// lane-contiguous dest; resulting ds_read bank conflicts are the m97 tradeoff).
#define BM 128
#define BN 128
#define BK 32

template <typename OutT>
__global__ __launch_bounds__(256) void gemm_bt_bias_kernel(
    const __bf16* __restrict__ A, const __bf16* __restrict__ Bt,
    const float* __restrict__ bias, OutT* __restrict__ C,
    int M, int N, int K) {
    __shared__ __bf16 As[BM][BK];  // 8 KB, 64B rows
    __shared__ __bf16 Bs[BN][BK];
    int tid  = threadIdx.x;
    int bm   = blockIdx.x;
    int bn   = blockIdx.y;
    int wave = tid >> 6;
    int lane = tid & 63;
    int wm   = (wave >> 1) * 64;
    int wn   = (wave & 1) * 64;
    int quad = lane >> 4;
    int l16  = lane & 15;
    int srow = wave * 16 + (lane >> 2);   // staging row within 64-row half
    int scol = (lane & 3) * 8;            // bf16 elements (16B chunk)

    f32x4 acc[4][4];
    f32x4 zero = {0.f, 0.f, 0.f, 0.f};
    #pragma unroll
    for (int i = 0; i < 4; ++i)
        #pragma unroll
        for (int j = 0; j < 4; ++j) acc[i][j] = zero;

    const __bf16* Abase = A  + (size_t)(bm * BM) * K;
    const __bf16* Bbase = Bt + (size_t)(bn * BN) * K;

    for (int k0 = 0; k0 < K; k0 += BK) {
        if (k0) __syncthreads();
        #pragma unroll
        for (int it = 0; it < 2; ++it) {
            int r = it * 64 + srow;
            GLD_LDS16(Abase + (size_t)r * K + k0 + scol, &As[it * 64 + wave * 16][0]);
            GLD_LDS16(Bbase + (size_t)r * K + k0 + scol, &Bs[it * 64 + wave * 16][0]);
        }
        __syncthreads();  // drains vmcnt -> LDS data visible

        bf16x8 a_frag[4], b_frag[4];
        #pragma unroll
        for (int i = 0; i < 4; ++i)
            a_frag[i] = *(bf16x8*)(&As[wm + i * 16 + l16][quad * 8]);
        #pragma unroll
        for (int j = 0; j < 4; ++j)
            b_frag[j] = *(bf16x8*)(&Bs[wn + j * 16 + l16][quad * 8]);
        #pragma unroll
        for (int i = 0; i < 4; ++i)
            #pragma unroll
            for (int j = 0; j < 4; ++j)
                acc[i][j] = __builtin_amdgcn_mfma_f32_16x16x32_bf16(
                    a_frag[i], b_frag[j], acc[i][j], 0, 0, 0);
    }

    // D layout (HW-verified m89/m91): row = quad*4+reg, col = l16
    #pragma unroll
    for (int i = 0; i < 4; ++i) {
        int row = bm * BM + wm + i * 16 + quad * 4;
        #pragma unroll
        for (int j = 0; j < 4; ++j) {
            int col  = bn * BN + wn + j * 16 + l16;
            float bv = bias[col];
            #pragma unroll
            for (int r = 0; r < 4; ++r)
                C[(size_t)(row + r) * N + col] = (OutT)(acc[i][j][r] + bv);
        }
    }
}

// ---------------------------------------------------------------- RoPE (in-place, bf16)
__global__ __launch_bounds__(256) void rope_kernel(
    __bf16* __restrict__ buf, const float* __restrict__ cosp,
    const float* __restrict__ sinp, int heads, int rowstride, int S, int total) {
    int idx = blockIdx.x * 256 + threadIdx.x;
    if (idx >= total) return;
    int d  = idx & 63;
    int t2 = idx >> 6;
    int h  = t2 % heads;
    int r  = t2 / heads;
    int s  = r & (S - 1);
    size_t base = (size_t)r * rowstride + h * 128;
    float x1 = (float)buf[base + d];
    float x2 = (float)buf[base + d + 64];
    float c  = cosp[s * 64 + d];
    float sn = sinp[s * 64 + d];
    buf[base + d]      = (__bf16)(x1 * c - x2 * sn);
    buf[base + d + 64] = (__bf16)(x1 * sn + x2 * c);
}

// ---------------------------------------------------------------- MFMA flash attention
// 4 waves/block, Q-tile 128 (wave owns rows q0+mt*64+w*16, mt=0,1).
// K/V frags read directly from global in B-operand layout; no __syncthreads.
// Softmax cross-lane via DPP row_ror (VALU pipe) — NOT ds_bpermute shuffles.
// l-sum deferred: per-lane partials in-loop, one DPP reduce at the end.
#define FB_K   64
#define PS_STR 72    // 64 keys + 8 pad

__global__ __launch_bounds__(256, 2) void flash_mfma_kernel(
    const __bf16* __restrict__ q,    // [B*S][2048], rope applied
    const __bf16* __restrict__ kv,   // [B*S][1024]: k cols 0..511 (roped)
    const __bf16* __restrict__ vtg,  // [(b*4+kvh)*128 + d][S]  (V transposed)
    __bf16* __restrict__ vo,         // [B*S][2048]
    const int* __restrict__ causal_p, int S) {
    __shared__ __bf16 Ps[4 * 32 * PS_STR];  // per-wave P transform buffer

    int tid  = threadIdx.x;
    int wave = tid >> 6;
    int lane = tid & 63;
    int quad = lane >> 4;
    int l16  = lane & 15;
    // id%8 -> (b,kvh) XCD affinity; qt slowest-varying, reversed -> heavy first
    int id   = blockIdx.x;
    int xcd  = id & 7;
    int b    = xcd >> 2;
    int kvh  = xcd & 3;
    int rest = id >> 3;          // 0..63
    int qt   = 15 - (rest >> 2); // heavy (high-qt) blocks dispatch first
    int h    = kvh * 4 + (rest & 3);
    int q0   = qt * 128;
    int causal = causal_p[0];
    const float SCALE = 0.08838834764831845f;  // 1/sqrt(128)

    // Q A-frags: lane holds row l16 of its 16-row tile, dims kc*32+quad*8..+7
    bf16x8 a_frag[2][4];
    #pragma unroll
    for (int mt = 0; mt < 2; ++mt) {
        size_t qbase = ((size_t)b * S + q0 + mt * 64 + wave * 16 + l16) * 2048
                       + h * 128 + quad * 8;
        #pragma unroll
        for (int kc = 0; kc < 4; ++kc)
            a_frag[mt][kc] = *(const bf16x8*)(q + qbase + kc * 32);
    }

    f32x4 o_acc[2][8];
    f32x4 zero4 = {0.f, 0.f, 0.f, 0.f};
    #pragma unroll
    for (int mt = 0; mt < 2; ++mt)
        #pragma unroll
        for (int dt = 0; dt < 8; ++dt) o_acc[mt][dt] = zero4;
    float m_[2][4], l_[2][4];  // m_: row max (uniform over l16); l_: PER-LANE partial
    #pragma unroll
    for (int mt = 0; mt < 2; ++mt)
        #pragma unroll
        for (int r = 0; r < 4; ++r) { m_[mt][r] = -1e30f; l_[mt][r] = 0.f; }

    const __bf16* kbase = kv  + ((size_t)b * S) * 1024 + kvh * 128;
    const __bf16* vbase = vtg + ((size_t)(b * 4 + kvh) * 128) * S;

    int ntiles = causal ? (2 * qt + 2) : (S / FB_K);
    for (int t = 0; t < ntiles; ++t) {
        int j0 = t * FB_K;

        // ---- issue ALL K loads up front (16 b128, independent)
        bf16x8 kf[4][4];
        #pragma unroll
        for (int jt = 0; jt < 4; ++jt) {
            const __bf16* kp = kbase + (size_t)(j0 + jt * 16 + l16) * 1024 + quad * 8;
            #pragma unroll
            for (int kc = 0; kc < 4; ++kc) kf[jt][kc] = *(const bf16x8*)(kp + kc * 32);
        }

        // ---- S = Q @ K^T
        f32x4 s_t[2][4];
        #pragma unroll
        for (int mt = 0; mt < 2; ++mt)
            #pragma unroll
            for (int jt = 0; jt < 4; ++jt) s_t[mt][jt] = zero4;
        #pragma unroll
        for (int jt = 0; jt < 4; ++jt)
            #pragma unroll
            for (int mt = 0; mt < 2; ++mt)
                #pragma unroll
                for (int kc = 0; kc < 4; ++kc)
                    s_t[mt][jt] = __builtin_amdgcn_mfma_f32_16x16x32_bf16(
                        a_frag[mt][kc], kf[jt][kc], s_t[mt][jt], 0, 0, 0);

        // ---- issue V loads now; latency hides behind softmax + P transform
        bf16x8 vf[8][2];
        #pragma unroll
        for (int dt = 0; dt < 8; ++dt) {
            const __bf16* vp = vbase + (size_t)(dt * 16 + l16) * S + j0 + quad * 8;
            vf[dt][0] = *(const bf16x8*)(vp);
            vf[dt][1] = *(const bf16x8*)(vp + 32);
        }

        // ---- scale + causal mask (only tiles touching the diagonal)
        int diag = causal && (t >= 2 * qt);
        #pragma unroll
        for (int mt = 0; mt < 2; ++mt) {
            int qrow = q0 + mt * 64 + wave * 16 + quad * 4;
            #pragma unroll
            for (int jt = 0; jt < 4; ++jt)
                #pragma unroll
                for (int r = 0; r < 4; ++r) {
                    float sv = s_t[mt][jt][r] * SCALE;
                    if (diag && (j0 + jt * 16 + l16 > qrow + r)) sv = -1e30f;
                    s_t[mt][jt][r] = sv;
                }
        }

        // ---- online softmax: DPP max-reduce, per-lane l partials (no shuffles)
        #pragma unroll
        for (int mt = 0; mt < 2; ++mt) {
            float alpha[4];
            #pragma unroll
            for (int r = 0; r < 4; ++r) {
                float v = fmaxf(fmaxf(s_t[mt][0][r], s_t[mt][1][r]),
                                fmaxf(s_t[mt][2][r], s_t[mt][3][r]));
                v = rowmax16(v);                       // DPP, 16-lane row == l16 group
                float m_new = fmaxf(m_[mt][r], v);
                alpha[r] = __expf(m_[mt][r] - m_new);
                m_[mt][r] = m_new;
                float rs = 0.f;
                #pragma unroll
                for (int jt = 0; jt < 4; ++jt) {
                    float p = __expf(s_t[mt][jt][r] - m_new);
                    s_t[mt][jt][r] = p;
                    rs += p;
                }
                l_[mt][r] = l_[mt][r] * alpha[r] + rs;  // per-lane partial
            }
            // P (C-layout) -> per-wave LDS (no barrier: private region)
            #pragma unroll
            for (int jt = 0; jt < 4; ++jt)
                #pragma unroll
                for (int r = 0; r < 4; ++r)
                    Ps[(wave * 32 + mt * 16 + quad * 4 + r) * PS_STR + jt * 16 + l16] =
                        (__bf16)s_t[mt][jt][r];
            // o rescale (VALU) overlaps the LDS writes
            #pragma unroll
            for (int dt = 0; dt < 8; ++dt)
                #pragma unroll
                for (int r = 0; r < 4; ++r) o_acc[mt][dt][r] *= alpha[r];
        }

        // ---- P A-frags back from LDS; PV with prefetched V frags
        bf16x8 p_frag[2][2];
        #pragma unroll
        for (int mt = 0; mt < 2; ++mt) {
            p_frag[mt][0] = *(bf16x8*)&Ps[(wave * 32 + mt * 16 + l16) * PS_STR + quad * 8];
            p_frag[mt][1] = *(bf16x8*)&Ps[(wave * 32 + mt * 16 + l16) * PS_STR + 32 + quad * 8];
        }
        #pragma unroll
        for (int dt = 0; dt < 8; ++dt)
            #pragma unroll
            for (int mt = 0; mt < 2; ++mt) {
                o_acc[mt][dt] = __builtin_amdgcn_mfma_f32_16x16x32_bf16(
                    p_frag[mt][0], vf[dt][0], o_acc[mt][dt], 0, 0, 0);
                o_acc[mt][dt] = __builtin_amdgcn_mfma_f32_16x16x32_bf16(
                    p_frag[mt][1], vf[dt][1], o_acc[mt][dt], 0, 0, 0);
            }
    }

    // ---- deferred l reduction (DPP) + normalize + store
    #pragma unroll
    for (int mt = 0; mt < 2; ++mt) {
        float invl[4];
        #pragma unroll
        for (int r = 0; r < 4; ++r) invl[r] = 1.f / rowsum16(l_[mt][r]);
        size_t obase = ((size_t)b * S + q0 + mt * 64 + wave * 16 + quad * 4) * 2048
                       + h * 128 + l16;
        #pragma unroll
        for (int dt = 0; dt < 8; ++dt)
            #pragma unroll
            for (int r = 0; r < 4; ++r)
                vo[obase + (size_t)r * 2048 + dt * 16] = (__bf16)(o_acc[mt][dt][r] * invl[r]);
    }
}

// ---------------------------------------------------------------- launch

extern "C" void kernel_launch(void* const* d_in, const int* in_sizes, int n_in,
                              void* d_out, int out_size, void* d_ws, size_t ws_size,
                              hipStream_t stream) {
    const float* x    = (const float*)d_in[0];
    const float* cosp = (const float*)d_in[1];
    const float* sinp = (const float*)d_in[2];
    const float* Wq   = (const float*)d_in[3];
    const float* bq   = (const float*)d_in[4];
    const float* Wkv  = (const float*)d_in[5];
    const float* bkv  = (const float*)d_in[6];
    const float* Wo   = (const float*)d_in[7];
    const float* bo   = (const float*)d_in[8];
    const int* causal = (const int*)d_in[9];
    float* out = (float*)d_out;

    const int B = 2, S = 2048;
    const int M = B * S;  // 4096

    // workspace layout (76 MB)
    char* w = (char*)d_ws;
    __bf16* x16   = (__bf16*)w; w += (size_t)M * 2048 * 2;     // 16 MB
    __bf16* Wqt   = (__bf16*)w; w += (size_t)2048 * 2048 * 2;  //  8 MB
    __bf16* Wkvt  = (__bf16*)w; w += (size_t)1024 * 2048 * 2;  //  4 MB
    __bf16* Wot   = (__bf16*)w; w += (size_t)2048 * 2048 * 2;  //  8 MB
    __bf16* qbuf  = (__bf16*)w; w += (size_t)M * 2048 * 2;     // 16 MB
    __bf16* kvbuf = (__bf16*)w; w += (size_t)M * 1024 * 2;     //  8 MB
    __bf16* vobuf = (__bf16*)w; w += (size_t)M * 2048 * 2;     // 16 MB
    __bf16* vtg   = Wqt;  // alias: Wqt dead after Q GEMM; vtg needs 4 MB <= 8 MB

    f32_to_bf16_kernel<<<(M * 2048) / (256 * 8), 256, 0, stream>>>(x, x16, (size_t)M * 2048);
    transpose_to_bf16_kernel<<<dim3(2048 / 32, 2048 / 32), dim3(32, 8), 0, stream>>>(Wq, Wqt, 2048, 2048);
    transpose_to_bf16_kernel<<<dim3(1024 / 32, 2048 / 32), dim3(32, 8), 0, stream>>>(Wkv, Wkvt, 2048, 1024);
    transpose_to_bf16_kernel<<<dim3(2048 / 32, 2048 / 32), dim3(32, 8), 0, stream>>>(Wo, Wot, 2048, 2048);
    gemm_bt_bias_kernel<__bf16><<<dim3(M / BM, 2048 / BN), 256, 0, stream>>>(x16, Wqt, bq, qbuf, M, 2048, 2048);
    gemm_bt_bias_kernel<__bf16><<<dim3(M / BM, 1024 / BN), 256, 0, stream>>>(x16, Wkvt, bkv, kvbuf, M, 1024, 2048);
    {
        int totq = M * 16 * 64;
        rope_kernel<<<(totq + 255) / 256, 256, 0, stream>>>(qbuf, cosp, sinp, 16, 2048, S, totq);
        int totk = M * 4 * 64;
        rope_kernel<<<(totk + 255) / 256, 256, 0, stream>>>(kvbuf, cosp, sinp, 4, 1024, S, totk);
    }
    transpose_v_kernel<<<dim3(S / 32, 128 / 32, B * 4), dim3(32, 8), 0, stream>>>(kvbuf, vtg, S);
    flash_mfma_kernel<<<dim3(512), 256, 0, stream>>>(qbuf, kvbuf, vtg, vobuf, causal, S);
    gemm_bt_bias_kernel<float><<<dim3(M / BM, 2048 / BN), 256, 0, stream>>>(vobuf, Wot, bo, out, M, 2048, 2048);
}

// Round 5
// 431.482 us; speedup vs baseline: 4.1464x; 1.0752x over previous
//
#include <hip/hip_runtime.h>
#include <hip/hip_bf16.h>

typedef __bf16 bf16x8 __attribute__((ext_vector_type(8)));
typedef float  f32x4  __attribute__((ext_vector_type(4)));
typedef unsigned int u32;

// async global->LDS, 16B/lane; LDS dest = wave-uniform base + lane*16 (m97/m104)
#define GLD_LDS16(gp, lp) __builtin_amdgcn_global_load_lds( \
    (const __attribute__((address_space(1))) u32*)(gp), \
    (__attribute__((address_space(3))) u32*)(lp), 16, 0, 0)

// DPP cyclic rotate within 16-lane rows (row_ror:N = 0x120|N) — VALU-pipe cross-lane
template<int CTRL>
__device__ __forceinline__ float dpp_rot(float x) {
    int y = __builtin_amdgcn_update_dpp(__float_as_int(x), __float_as_int(x),
                                        CTRL, 0xF, 0xF, false);
    return __int_as_float(y);
}
__device__ __forceinline__ float rowmax16(float x) {
    x = fmaxf(x, dpp_rot<0x121>(x));
    x = fmaxf(x, dpp_rot<0x122>(x));
    x = fmaxf(x, dpp_rot<0x124>(x));
    x = fmaxf(x, dpp_rot<0x128>(x));
    return x;
}
__device__ __forceinline__ float rowsum16(float x) {
    x += dpp_rot<0x121>(x);
    x += dpp_rot<0x122>(x);
    x += dpp_rot<0x124>(x);
    x += dpp_rot<0x128>(x);
    return x;
}

// ---------------------------------------------------------------- converts

__global__ __launch_bounds__(256) void f32_to_bf16_kernel(
    const float* __restrict__ in, __bf16* __restrict__ out, size_t n) {
    size_t i = ((size_t)blockIdx.x * 256 + threadIdx.x) * 8;
    if (i >= n) return;
    float4 a = *(const float4*)(in + i);
    float4 b = *(const float4*)(in + i + 4);
    bf16x8 v;
    v[0] = (__bf16)a.x; v[1] = (__bf16)a.y; v[2] = (__bf16)a.z; v[3] = (__bf16)a.w;
    v[4] = (__bf16)b.x; v[5] = (__bf16)b.y; v[6] = (__bf16)b.z; v[7] = (__bf16)b.w;
    *(bf16x8*)(out + i) = v;
}

// W[K][N] fp32  ->  Wt[N][K] bf16   (32x32 LDS tile transpose)
__global__ __launch_bounds__(256) void transpose_to_bf16_kernel(
    const float* __restrict__ W, __bf16* __restrict__ Wt, int K, int N) {
    __shared__ float tile[32][33];
    int n0 = blockIdx.x * 32, k0 = blockIdx.y * 32;
    int tx = threadIdx.x, ty = threadIdx.y;  // 32 x 8
    #pragma unroll
    for (int i = 0; i < 32; i += 8)
        tile[ty + i][tx] = W[(size_t)(k0 + ty + i) * N + n0 + tx];
    __syncthreads();
    #pragma unroll
    for (int i = 0; i < 32; i += 8)
        Wt[(size_t)(n0 + ty + i) * K + k0 + tx] = (__bf16)tile[tx][ty + i];
}

// bqkv = concat(bq[2048], bkv[1024])
__global__ __launch_bounds__(256) void concat_bias_kernel(
    const float* __restrict__ bq, const float* __restrict__ bkv,
    float* __restrict__ bqkv) {
    int i = blockIdx.x * 256 + threadIdx.x;
    if (i < 2048) bqkv[i] = bq[i];
    else if (i < 3072) bqkv[i] = bkv[i - 2048];
}

// V cols of qkv [b*S+s][3072] (cols 2560..3071) -> Vt[(b*4+kvh)*128 + d][S]
__global__ __launch_bounds__(256) void transpose_v_kernel(
    const __bf16* __restrict__ qkv, __bf16* __restrict__ vtg, int S) {
    __shared__ __bf16 tile[32][33];
    int s0 = blockIdx.x * 32, d0 = blockIdx.y * 32, z = blockIdx.z;  // z = b*4+kvh
    int b = z >> 2, kvh = z & 3;
    int tx = threadIdx.x, ty = threadIdx.y;  // 32 x 8
    #pragma unroll
    for (int i = 0; i < 32; i += 8)
        tile[ty + i][tx] =
            qkv[((size_t)b * S + s0 + ty + i) * 3072 + 2560 + kvh * 128 + d0 + tx];
    __syncthreads();
    #pragma unroll
    for (int i = 0; i < 32; i += 8)
        vtg[((size_t)z * 128 + d0 + ty + i) * S + s0 + tx] = tile[tx][ty + i];
}

// ---------------------------------------------------------------- GEMM (m97: BK=64)
// C[M][N] = A[M][K](bf16) @ Bt[N][K](bf16)^T + bias[N], fp32 accumulate.
// Per wave-iter: 32 MFMA, 16 ds_read_b128, 8 global_load_lds_dwordx4.
#define BM 128
#define BN 128
#define BK 64

template <typename OutT>
__global__ __launch_bounds__(256) void gemm_bt_bias_kernel(
    const __bf16* __restrict__ A, const __bf16* __restrict__ Bt,
    const float* __restrict__ bias, OutT* __restrict__ C,
    int M, int N, int K) {
    __shared__ __bf16 As[BM * BK];  // 16 KB, 128B rows, unpadded (DMA dest)
    __shared__ __bf16 Bs[BN * BK];
    int tid  = threadIdx.x;
    int bm   = blockIdx.x;
    int bn   = blockIdx.y;
    int wave = tid >> 6;
    int lane = tid & 63;
    int wm   = (wave >> 1) * 64;
    int wn   = (wave & 1) * 64;
    int quad = lane >> 4;
    int l16  = lane & 15;
    int gr   = wave * 32 + (lane >> 3);   // staging row (+i*8)
    int gc   = (lane & 7) * 8;            // staging col (bf16 elems)

    f32x4 acc[4][4];
    f32x4 zero = {0.f, 0.f, 0.f, 0.f};
    #pragma unroll
    for (int i = 0; i < 4; ++i)
        #pragma unroll
        for (int j = 0; j < 4; ++j) acc[i][j] = zero;

    const __bf16* Abase = A  + (size_t)(bm * BM) * K;
    const __bf16* Bbase = Bt + (size_t)(bn * BN) * K;

    for (int k0 = 0; k0 < K; k0 += BK) {
        if (k0) __syncthreads();
        #pragma unroll
        for (int i = 0; i < 4; ++i) {
            GLD_LDS16(Abase + (size_t)(gr + i * 8) * K + k0 + gc,
                      &As[(wave * 32 + i * 8) * BK]);
            GLD_LDS16(Bbase + (size_t)(gr + i * 8) * K + k0 + gc,
                      &Bs[(wave * 32 + i * 8) * BK]);
        }
        __syncthreads();  // drains vmcnt -> LDS data visible

        bf16x8 af[4][2], bf[4][2];
        #pragma unroll
        for (int i = 0; i < 4; ++i)
            #pragma unroll
            for (int kc = 0; kc < 2; ++kc)
                af[i][kc] = *(bf16x8*)&As[(wm + i * 16 + l16) * BK + kc * 32 + quad * 8];
        #pragma unroll
        for (int j = 0; j < 4; ++j)
            #pragma unroll
            for (int kc = 0; kc < 2; ++kc)
                bf[j][kc] = *(bf16x8*)&Bs[(wn + j * 16 + l16) * BK + kc * 32 + quad * 8];
        #pragma unroll
        for (int kc = 0; kc < 2; ++kc)
            #pragma unroll
            for (int i = 0; i < 4; ++i)
                #pragma unroll
                for (int j = 0; j < 4; ++j)
                    acc[i][j] = __builtin_amdgcn_mfma_f32_16x16x32_bf16(
                        af[i][kc], bf[j][kc], acc[i][j], 0, 0, 0);
    }

    // D layout (HW-verified m89/m91): row = quad*4+reg, col = l16
    #pragma unroll
    for (int i = 0; i < 4; ++i) {
        int row = bm * BM + wm + i * 16 + quad * 4;
        #pragma unroll
        for (int j = 0; j < 4; ++j) {
            int col  = bn * BN + wn + j * 16 + l16;
            float bv = bias[col];
            #pragma unroll
            for (int r = 0; r < 4; ++r)
                C[(size_t)(row + r) * N + col] = (OutT)(acc[i][j][r] + bv);
        }
    }
}

// ---------------------------------------------------------------- RoPE (in-place, bf16)
__global__ __launch_bounds__(256) void rope_kernel(
    __bf16* __restrict__ buf, const float* __restrict__ cosp,
    const float* __restrict__ sinp, int heads, int rowstride, int coloff,
    int S, int total) {
    int idx = blockIdx.x * 256 + threadIdx.x;
    if (idx >= total) return;
    int d  = idx & 63;
    int t2 = idx >> 6;
    int h  = t2 % heads;
    int r  = t2 / heads;
    int s  = r & (S - 1);
    size_t base = (size_t)r * rowstride + coloff + h * 128;
    float x1 = (float)buf[base + d];
    float x2 = (float)buf[base + d + 64];
    float c  = cosp[s * 64 + d];
    float sn = sinp[s * 64 + d];
    buf[base + d]      = (__bf16)(x1 * c - x2 * sn);
    buf[base + d + 64] = (__bf16)(x1 * sn + x2 * c);
}

// ---------------------------------------------------------------- MFMA flash attention
// 4 waves/block, Q-tile 64 rows (16/wave). Two phases per block: Q-tiles
// qt=pair and qt=31-pair -> uniform 33 causal tile-iterations per block.
// K: double-buffered LDS via global_load_lds (zero-VGPR prefetch, issued a
// full iteration before the barrier that drains it). Swizzled layout
// [(jt*4+kc)*512 + lane*8] is lane-linear for both DMA and frag ds_read_b128.
// V: register prefetch from dim-major vtg, issued at iter start, consumed
// after softmax. Softmax cross-lane via DPP; l-sum deferred to epilogue.
#define PS_STR 72

__global__ __launch_bounds__(256, 2) void flash_mfma_kernel(
    const __bf16* __restrict__ qkv,  // [B*S][3072]: q(0..2047)|k(2048..2559)|v
    const __bf16* __restrict__ vtg,  // [(b*4+kvh)*128 + d][S]  (V transposed)
    __bf16* __restrict__ vo,         // [B*S][2048]
    const int* __restrict__ causal_p, int S) {
    __shared__ __bf16 Ks[2][64 * 128];       // 2 x 16 KB, swizzled
    __shared__ __bf16 Ps[4 * 16 * PS_STR];   // 9 KB, per-wave P transform

    const int QKV = 3072;
    int tid  = threadIdx.x;
    int wave = tid >> 6;
    int lane = tid & 63;
    int quad = lane >> 4;
    int l16  = lane & 15;
    int id   = blockIdx.x;
    int xcd  = id & 7;           // id%8 -> (b,kvh): XCD L2 affinity
    int b    = xcd >> 2;
    int kvh  = xcd & 3;
    int rest = id >> 3;          // 0..63
    int hh   = rest & 3;
    int pair = rest >> 2;        // 0..15
    int h    = kvh * 4 + hh;
    int causal = causal_p[0];
    const float SCALE = 0.08838834764831845f;  // 1/sqrt(128)

    const __bf16* vB = vtg + ((size_t)(b * 4 + kvh) * 128) * S;

    #pragma unroll 1
    for (int phase = 0; phase < 2; ++phase) {
        int qt = phase ? (31 - pair) : pair;
        int q0 = qt * 64;
        int nt = causal ? (qt + 1) : (S / 64);

        // Q A-frags: lane holds row l16 of the wave's 16-row tile
        bf16x8 a_frag[4];
        size_t qrow = ((size_t)b * S + q0 + wave * 16 + l16) * QKV + h * 128 + quad * 8;
        #pragma unroll
        for (int kc = 0; kc < 4; ++kc)
            a_frag[kc] = *(const bf16x8*)(qkv + qrow + kc * 32);

        f32x4 o_acc[8];
        f32x4 zero4 = {0.f, 0.f, 0.f, 0.f};
        #pragma unroll
        for (int dt = 0; dt < 8; ++dt) o_acc[dt] = zero4;
        float m_[4], l_[4];  // m_: row max; l_: PER-LANE partial sum
        #pragma unroll
        for (int r = 0; r < 4; ++r) { m_[r] = -1e30f; l_[r] = 0.f; }
        int qrow_d = q0 + wave * 16 + quad * 4;

        __syncthreads();  // protect Ks from previous phase's readers
        // prologue: DMA K(0) -> Ks[0]; wave w stages keys w*16..w*16+15
        {
            size_t kg = ((size_t)b * S + wave * 16 + l16) * QKV + 2048 + kvh * 128 + quad * 8;
            #pragma unroll
            for (int kc = 0; kc < 4; ++kc)
                GLD_LDS16(qkv + kg + kc * 32, &Ks[0][(wave * 4 + kc) * 512]);
        }

        for (int t = 0; t < nt; ++t) {
            int cur = t & 1;
            __syncthreads();  // drains vmcnt: K(t) DMA complete; syncs buffers
            if (t + 1 < nt) {  // prefetch K(t+1) into the other buffer
                size_t kg = ((size_t)b * S + (t + 1) * 64 + wave * 16 + l16) * QKV
                            + 2048 + kvh * 128 + quad * 8;
                #pragma unroll
                for (int kc = 0; kc < 4; ++kc)
                    GLD_LDS16(qkv + kg + kc * 32, &Ks[1 - cur][(wave * 4 + kc) * 512]);
            }
            int j0 = t * 64;

            // V register prefetch (consumed after softmax -> latency hidden)
            bf16x8 vf[8][2];
            #pragma unroll
            for (int dt = 0; dt < 8; ++dt) {
                const __bf16* vp = vB + (size_t)(dt * 16 + l16) * S + j0 + quad * 8;
                vf[dt][0] = *(const bf16x8*)(vp);
                vf[dt][1] = *(const bf16x8*)(vp + 32);
            }

            // S = Q @ K^T  (K frags from swizzled LDS, conflict-free)
            f32x4 s_t[4];
            #pragma unroll
            for (int jt = 0; jt < 4; ++jt) s_t[jt] = zero4;
            #pragma unroll
            for (int jt = 0; jt < 4; ++jt)
                #pragma unroll
                for (int kc = 0; kc < 4; ++kc) {
                    bf16x8 kf = *(bf16x8*)&Ks[cur][(jt * 4 + kc) * 512 + lane * 8];
                    s_t[jt] = __builtin_amdgcn_mfma_f32_16x16x32_bf16(
                        a_frag[kc], kf, s_t[jt], 0, 0, 0);
                }

            // scale + causal mask (diagonal tile only)
            int diag = causal && (t == nt - 1);
            #pragma unroll
            for (int jt = 0; jt < 4; ++jt)
                #pragma unroll
                for (int r = 0; r < 4; ++r) {
                    float sv = s_t[jt][r] * SCALE;
                    if (diag && (j0 + jt * 16 + l16 > qrow_d + r)) sv = -1e30f;
                    s_t[jt][r] = sv;
                }

            // online softmax: DPP max-reduce, per-lane l partials
            float alpha[4];
            #pragma unroll
            for (int r = 0; r < 4; ++r) {
                float v = fmaxf(fmaxf(s_t[0][r], s_t[1][r]),
                                fmaxf(s_t[2][r], s_t[3][r]));
                v = rowmax16(v);
                float m_new = fmaxf(m_[r], v);
                alpha[r] = __expf(m_[r] - m_new);
                m_[r] = m_new;
                float rs = 0.f;
                #pragma unroll
                for (int jt = 0; jt < 4; ++jt) {
                    float p = __expf(s_t[jt][r] - m_new);
                    s_t[jt][r] = p;
                    rs += p;
                }
                l_[r] = l_[r] * alpha[r] + rs;
            }
            // P (C-layout) -> per-wave LDS region (no barrier needed)
            #pragma unroll
            for (int jt = 0; jt < 4; ++jt)
                #pragma unroll
                for (int r = 0; r < 4; ++r)
                    Ps[(wave * 16 + quad * 4 + r) * PS_STR + jt * 16 + l16] =
                        (__bf16)s_t[jt][r];
            #pragma unroll
            for (int dt = 0; dt < 8; ++dt)
                #pragma unroll
                for (int r = 0; r < 4; ++r) o_acc[dt][r] *= alpha[r];

            // P A-frags back from LDS; PV with prefetched V frags
            bf16x8 p0 = *(bf16x8*)&Ps[(wave * 16 + l16) * PS_STR + quad * 8];
            bf16x8 p1 = *(bf16x8*)&Ps[(wave * 16 + l16) * PS_STR + 32 + quad * 8];
            #pragma unroll
            for (int dt = 0; dt < 8; ++dt) {
                o_acc[dt] = __builtin_amdgcn_mfma_f32_16x16x32_bf16(
                    p0, vf[dt][0], o_acc[dt], 0, 0, 0);
                o_acc[dt] = __builtin_amdgcn_mfma_f32_16x16x32_bf16(
                    p1, vf[dt][1], o_acc[dt], 0, 0, 0);
            }
        }

        // deferred l reduction (DPP) + normalize + store
        float invl[4];
        #pragma unroll
        for (int r = 0; r < 4; ++r) invl[r] = 1.f / rowsum16(l_[r]);
        size_t obase = ((size_t)b * S + q0 + wave * 16 + quad * 4) * 2048
                       + h * 128 + l16;
        #pragma unroll
        for (int dt = 0; dt < 8; ++dt)
            #pragma unroll
            for (int r = 0; r < 4; ++r)
                vo[obase + (size_t)r * 2048 + dt * 16] = (__bf16)(o_acc[dt][r] * invl[r]);
    }
}

// ---------------------------------------------------------------- launch

extern "C" void kernel_launch(void* const* d_in, const int* in_sizes, int n_in,
                              void* d_out, int out_size, void* d_ws, size_t ws_size,
                              hipStream_t stream) {
    const float* x    = (const float*)d_in[0];
    const float* cosp = (const float*)d_in[1];
    const float* sinp = (const float*)d_in[2];
    const float* Wq   = (const float*)d_in[3];
    const float* bq   = (const float*)d_in[4];
    const float* Wkv  = (const float*)d_in[5];
    const float* bkv  = (const float*)d_in[6];
    const float* Wo   = (const float*)d_in[7];
    const float* bo   = (const float*)d_in[8];
    const int* causal = (const int*)d_in[9];
    float* out = (float*)d_out;

    const int B = 2, S = 2048;
    const int M = B * S;  // 4096

    // workspace layout (~60 MB)
    char* w = (char*)d_ws;
    __bf16* x16    = (__bf16*)w; w += (size_t)M * 2048 * 2;     // 16 MB; later = vobuf
    __bf16* Wqkvt  = (__bf16*)w; w += (size_t)3072 * 2048 * 2;  // 12 MB; later = vtg
    __bf16* Wot    = (__bf16*)w; w += (size_t)2048 * 2048 * 2;  //  8 MB
    float*  bqkv   = (float*)w;  w += (size_t)3072 * 4;         // 12 KB
    __bf16* qkvbuf = (__bf16*)w; w += (size_t)M * 3072 * 2;     // 24 MB
    __bf16* vobuf  = x16;    // alias: x16 dead after fused GEMM
    __bf16* vtg    = Wqkvt;  // alias: Wqkvt dead after fused GEMM (4 MB <= 12 MB)

    f32_to_bf16_kernel<<<(M * 2048) / (256 * 8), 256, 0, stream>>>(x, x16, (size_t)M * 2048);
    // fused weight: Wqkvt rows 0..2047 = Wq^T, rows 2048..3071 = Wkv^T
    transpose_to_bf16_kernel<<<dim3(2048 / 32, 2048 / 32), dim3(32, 8), 0, stream>>>(Wq, Wqkvt, 2048, 2048);
    transpose_to_bf16_kernel<<<dim3(1024 / 32, 2048 / 32), dim3(32, 8), 0, stream>>>(Wkv, Wqkvt + (size_t)2048 * 2048, 2048, 1024);
    transpose_to_bf16_kernel<<<dim3(2048 / 32, 2048 / 32), dim3(32, 8), 0, stream>>>(Wo, Wot, 2048, 2048);
    concat_bias_kernel<<<12, 256, 0, stream>>>(bq, bkv, bqkv);
    // fused QKV projection: [4096][3072]
    gemm_bt_bias_kernel<__bf16><<<dim3(M / BM, 3072 / BN), 256, 0, stream>>>(x16, Wqkvt, bqkv, qkvbuf, M, 3072, 2048);
    // RoPE on q (16 heads, col 0) and k (4 heads, col 2048)
    {
        int totq = M * 16 * 64;
        rope_kernel<<<(totq + 255) / 256, 256, 0, stream>>>(qkvbuf, cosp, sinp, 16, 3072, 0, S, totq);
        int totk = M * 4 * 64;
        rope_kernel<<<(totk + 255) / 256, 256, 0, stream>>>(qkvbuf, cosp, sinp, 4, 3072, 2048, S, totk);
    }
    // V -> dim-major global layout
    transpose_v_kernel<<<dim3(S / 32, 128 / 32, B * 4), dim3(32, 8), 0, stream>>>(qkvbuf, vtg, S);
    // 512 blocks: id%8 -> (b,kvh); paired Q-tiles -> uniform 33 iters/block
    flash_mfma_kernel<<<dim3(512), 256, 0, stream>>>(qkvbuf, vtg, vobuf, causal, S);
    // output projection (fp32 out)
    gemm_bt_bias_kernel<float><<<dim3(M / BM, 2048 / BN), 256, 0, stream>>>(vobuf, Wot, bo, out, M, 2048, 2048);
}